// Round 6
// baseline (954.047 us; speedup 1.0000x reference)
//
#include <hip/hip_runtime.h>
#include <hip/hip_fp16.h>

#define T_SEQ 2048
#define HID   50
#define KP    64      // k: 0..49 = h, 50..62 = onehot, 63 = bias
#define MBG   4       // batch rows per group
#define NBLK  256     // 2048 / 8 -> 1 block/CU, 8 rows = 2 groups x 4
#define NTHR  256     // 4 waves
#define HSTR  80      // ushorts per h row (160 B)
#define BUFB  (MBG*HSTR)   // 320 ushorts per buffer per group

#define NLOG2E  1.4426950408889634f   // gates scaled by -log2e (g-gate by -2log2e) in B
#define N2LOG2E 2.8853900817779268f

typedef __attribute__((ext_vector_type(8))) _Float16 half8;
typedef __attribute__((ext_vector_type(4))) float    f32x4;

__device__ __forceinline__ ushort f16b(float f){ return __half_as_ushort(__float2half(f)); }
__device__ __forceinline__ float rcp_(float x){ return __builtin_amdgcn_rcpf(x); }
__device__ __forceinline__ float ex2_(float x){ return __builtin_amdgcn_exp2f(x); }

// Bm[256 cols][64 k] f16.  col = w*64 + g*16 + c16 encodes unit u = w*16+c16, gate g
// (g: 0=i,1=f,2=g,3=o).  Row r = g*50+u.  ALL entries pre-scaled by -log2e (g-gate
// by -2log2e) so the MFMA emits gates in exp2 domain.
__global__ void build_B(const float* __restrict__ embed, const float* __restrict__ Wih,
                        const float* __restrict__ Whh, const float* __restrict__ bih,
                        const float* __restrict__ bhh, ushort* __restrict__ Bm) {
    int idx = blockIdx.x * blockDim.x + threadIdx.x;
    if (idx >= 256 * KP) return;
    int col = idx >> 6, k = idx & 63;
    int wq = col >> 6, g = (col >> 4) & 3, cc = col & 15;
    int u = wq * 16 + cc;
    ushort v = 0;
    if (u < HID) {
        int r = g * HID + u;
        float s = (g == 2) ? -N2LOG2E : -NLOG2E;
        if (k < HID) {
            v = f16b(s * Whh[r * HID + k]);
        } else if (k < 63) {
            float t = 0.f;
            for (int e = 0; e < HID; ++e)
                t = fmaf(embed[(k - 50) * HID + e], Wih[r * HID + e], t);
            v = f16b(s * t);
        } else {
            v = f16b(s * (bih[r] + bhh[r]));
        }
    }
    Bm[idx] = v;
}

// 1 block/CU, 8 rows as TWO independent 4-row groups in the same wave: explicit ILP
// (group1 MFMAs/acts fill group0's latency gaps in-order, no scheduler luck needed).
// B shared in registers across groups. Tokens preloaded to LDS (u8): zero global ops
// in the loop -> barrier drains lgkmcnt only. 1 barrier/step.
__global__ __launch_bounds__(NTHR, 1) void lstm_dual(
    const int*    __restrict__ x,
    const ushort* __restrict__ Bm,
    const float*  __restrict__ W1,
    const float*  __restrict__ b1,
    const float*  __restrict__ W2,
    const float*  __restrict__ b2,
    float*        __restrict__ out)
{
    const int t   = threadIdx.x;
    const int w   = t >> 6;
    const int l   = t & 63;
    const int q   = l >> 4;
    const int c16 = l & 15;
    const int u   = w * 16 + c16;          // unit handled by this lane (group row = q)

    __shared__ __align__(16) ushort hb0[2 * BUFB];    // group0 h, double-buffered
    __shared__ __align__(16) ushort hb1[2 * BUFB];    // group1
    __shared__ __align__(16) unsigned char tokL[8 * T_SEQ];   // 16 KiB token cache
    __shared__ float zb[HID * 8];

    // B fragments: wave w owns tiles 4w..4w+3 (gate j), col c16 — shared by both groups
    half8 bf[4][2];
    {
        const ushort* bp = Bm + (w * 64 + c16) * KP + q * 8;
        #pragma unroll
        for (int j = 0; j < 4; ++j) {
            bf[j][0] = *(const half8*)(bp + j * 16 * KP);
            bf[j][1] = *(const half8*)(bp + j * 16 * KP + 32);
        }
    }
    #pragma unroll
    for (int j = 0; j < 4; ++j)
        asm volatile("" : "+v"(bf[j][0]), "+v"(bf[j][1]));

    // Token preload: rows are consecutive -> flat coalesced int4 copy, pack to u8
    {
        const int4* xs = (const int4*)(x + (long)blockIdx.x * 8 * T_SEQ);
        for (int i = t; i < 8 * T_SEQ / 4; i += NTHR) {
            int4 v = xs[i];
            uint pk = (uint)(v.x & 0xFF) | ((uint)(v.y & 0xFF) << 8) |
                      ((uint)(v.z & 0xFF) << 16) | ((uint)(v.w & 0xFF) << 24);
            *(uint*)(tokL + i * 4) = pk;
        }
    }
    for (int i = t; i < 2 * BUFB; i += NTHR) { hb0[i] = 0; hb1[i] = 0; }
    __syncthreads();

    // init bias + step-0/1 onehots for both groups (wave w: rows w and 4+w)
    int tA0, tA1, tA2, tB0, tB1, tB2;
    {
        int k00 = tokL[w * T_SEQ + 0],       k01 = tokL[w * T_SEQ + 1];
        int k10 = tokL[(4 + w) * T_SEQ + 0], k11 = tokL[(4 + w) * T_SEQ + 1];
        if (l == 0) {
            hb0[0 * BUFB + w * HSTR + 63] = 0x3C00;
            hb0[1 * BUFB + w * HSTR + 63] = 0x3C00;
            hb0[0 * BUFB + w * HSTR + 50 + k00] = 0x3C00;
            hb0[1 * BUFB + w * HSTR + 50 + k01] = 0x3C00;
            hb1[0 * BUFB + w * HSTR + 63] = 0x3C00;
            hb1[1 * BUFB + w * HSTR + 63] = 0x3C00;
            hb1[0 * BUFB + w * HSTR + 50 + k10] = 0x3C00;
            hb1[1 * BUFB + w * HSTR + 50 + k11] = 0x3C00;
        }
        tA0 = k01; tA1 = k00; tA2 = k01;
        tB0 = k11; tB1 = k10; tB2 = k11;
    }
    __syncthreads();

    // A row m = h[m>>2]: quadrant lanes 4-lane-broadcast, 2-way banks = free
    const ushort* ar0 = hb0 + (c16 >> 2) * HSTR + q * 8;
    const ushort* ar1 = hb1 + (c16 >> 2) * HSTR + q * 8;
    ushort*       wr0 = hb0 + q * HSTR + u;
    ushort*       wr1 = hb1 + q * HSTR + u;
    const unsigned char* tp0 = tokL + w * T_SEQ;
    const unsigned char* tp1 = tokL + (4 + w) * T_SEQ;

    float cs0 = 0.f, cs1 = 0.f;            // cs = -2*log2e * c  (pre-scaled domain)

#define MFMA_(A,B,C) __builtin_amdgcn_mfma_f32_16x16x32_f16((A),(B),(C),0,0,0)
#define STEP(P) do {                                                              \
        int it = step + 2 + (P); if (it > T_SEQ - 1) it = T_SEQ - 1;              \
        int tn0 = tp0[it];                       /* LDS broadcast reads */        \
        int tn1 = tp1[it];                                                        \
        half8 a00 = *(const half8*)(ar0 + (P) * BUFB);                            \
        half8 a01 = *(const half8*)(ar0 + (P) * BUFB + 32);                       \
        half8 a10 = *(const half8*)(ar1 + (P) * BUFB);                            \
        half8 a11 = *(const half8*)(ar1 + (P) * BUFB + 32);                       \
        const f32x4 zz = {0.f, 0.f, 0.f, 0.f};                                    \
        f32x4 z0 = MFMA_(a00, bf[0][0], zz); z0 = MFMA_(a01, bf[0][1], z0);       \
        f32x4 z1 = MFMA_(a00, bf[1][0], zz); z1 = MFMA_(a01, bf[1][1], z1);       \
        f32x4 z2 = MFMA_(a00, bf[2][0], zz); z2 = MFMA_(a01, bf[2][1], z2);       \
        f32x4 z3 = MFMA_(a00, bf[3][0], zz); z3 = MFMA_(a01, bf[3][1], z3);       \
        f32x4 y0 = MFMA_(a10, bf[0][0], zz); y0 = MFMA_(a11, bf[0][1], y0);       \
        f32x4 y1 = MFMA_(a10, bf[1][0], zz); y1 = MFMA_(a11, bf[1][1], y1);       \
        f32x4 y2 = MFMA_(a10, bf[2][0], zz); y2 = MFMA_(a11, bf[2][1], y2);       \
        f32x4 y3 = MFMA_(a10, bf[3][0], zz); y3 = MFMA_(a11, bf[3][1], y3);       \
        /* group0 act: z = -log2e*gate (g: -2log2e); clamp caps inf-NaN paths */  \
        float pi0 = ex2_(fminf(z0[0], 30.f));                                     \
        float pf0 = ex2_(fminf(z1[0], 30.f));                                     \
        float qg0 = ex2_(fminf(z2[0], 30.f));                                     \
        float Df0 = 1.f + pf0;                                                    \
        float D20 = (1.f + pi0) * (1.f + qg0);                                    \
        float ivA = rcp_(Df0 * D20);                                              \
        float fv0 = ivA * D20;                                                    \
        float ig0 = ivA * Df0 * fmaf(N2LOG2E, qg0, -N2LOG2E);                     \
        cs0 = fmaf(fv0, cs0, ig0);                                                \
        float po0 = ex2_(fminf(z3[0], 30.f));                                     \
        float qc0 = ex2_(fminf(cs0, 30.f));                                       \
        float ivB = rcp_((1.f + po0) * (1.f + qc0));                              \
        float h0  = ivB * (1.f - qc0);                                            \
        /* group1 act (independent chain, interleaves on trans pipe) */           \
        float pi1 = ex2_(fminf(y0[0], 30.f));                                     \
        float pf1 = ex2_(fminf(y1[0], 30.f));                                     \
        float qg1 = ex2_(fminf(y2[0], 30.f));                                     \
        float Df1 = 1.f + pf1;                                                    \
        float D21 = (1.f + pi1) * (1.f + qg1);                                    \
        float ivC = rcp_(Df1 * D21);                                              \
        float fv1 = ivC * D21;                                                    \
        float ig1 = ivC * Df1 * fmaf(N2LOG2E, qg1, -N2LOG2E);                     \
        cs1 = fmaf(fv1, cs1, ig1);                                                \
        float po1 = ex2_(fminf(y3[0], 30.f));                                     \
        float qc1 = ex2_(fminf(cs1, 30.f));                                       \
        float ivD = rcp_((1.f + po1) * (1.f + qc1));                              \
        float h1  = ivD * (1.f - qc1);                                            \
        if (u < HID) {                                                            \
            wr0[(1 - (P)) * BUFB] = f16b(h0);                                     \
            wr1[(1 - (P)) * BUFB] = f16b(h1);                                     \
        }                                                                         \
        if (l == 0) {                                                             \
            ushort* p0 = hb0 + (1 - (P)) * BUFB + w * HSTR + 50;                  \
            p0[tA0] = 0;  p0[tA2] = 0x3C00;                                       \
            ushort* p1 = hb1 + (1 - (P)) * BUFB + w * HSTR + 50;                  \
            p1[tB0] = 0;  p1[tB2] = 0x3C00;                                       \
        }                                                                         \
        tA0 = tA1; tA1 = tA2; tA2 = tn0;                                          \
        tB0 = tB1; tB1 = tB2; tB2 = tn1;                                          \
        __syncthreads();                                                          \
    } while (0)

    #pragma unroll 1
    for (int step = 0; step < T_SEQ; step += 2) {
        STEP(0);
        STEP(1);
    }
#undef STEP
#undef MFMA_

    // Epilogue MLP: final h in buffer 0 of each group (last step wrote it), synced.
    for (int idx = t; idx < 8 * HID; idx += NTHR) {
        int m = idx & 7, uu = idx >> 3;
        const ushort* hr = (m < 4 ? hb0 : hb1) + (m & 3) * HSTR;
        float a = b1[uu];
        #pragma unroll 10
        for (int k = 0; k < HID; ++k)
            a = fmaf(W1[uu * HID + k], __half2float(__ushort_as_half(hr[k])), a);
        zb[uu * 8 + m] = fmaxf(a, 0.f);
    }
    __syncthreads();
    if (t < 8) {
        float a = b2[0];
        #pragma unroll 10
        for (int j = 0; j < HID; ++j)
            a = fmaf(W2[j], zb[j * 8 + t], a);
        out[blockIdx.x * 8 + t] = a;
    }
}

extern "C" void kernel_launch(void* const* d_in, const int* in_sizes, int n_in,
                              void* d_out, int out_size, void* d_ws, size_t ws_size,
                              hipStream_t stream) {
    const int*   x     = (const int*)  d_in[0];
    const float* embed = (const float*)d_in[1];
    const float* W_ih  = (const float*)d_in[2];
    const float* W_hh  = (const float*)d_in[3];
    const float* b_ih  = (const float*)d_in[4];
    const float* b_hh  = (const float*)d_in[5];
    const float* W1    = (const float*)d_in[6];
    const float* b1    = (const float*)d_in[7];
    const float* W2    = (const float*)d_in[8];
    const float* b2    = (const float*)d_in[9];
    float* out = (float*)d_out;

    ushort* Bm = (ushort*)d_ws;   // 256*64*2 = 32768 B scratch

    build_B<<<(256 * KP + NTHR - 1) / NTHR, NTHR, 0, stream>>>(
        embed, W_ih, W_hh, b_ih, b_hh, Bm);

    lstm_dual<<<NBLK, NTHR, 0, stream>>>(
        x, Bm, W1, b1, W2, b2, out);
}

// Round 7
// 748.349 us; speedup vs baseline: 1.2749x; 1.2749x over previous
//
#include <hip/hip_runtime.h>
#include <hip/hip_fp16.h>

#define T_SEQ 2048
#define HID   50
#define KP    64      // k: 0..49 = h, 50..62 = onehot, 63 = bias
#define MB    8       // batch rows per block (16 A-rows = 8 real x 2 dup)
#define NBLK  256     // 2048 / MB -> 1 block/CU
#define NTHR  512     // 8 waves -> 2 waves/SIMD
#define HSTR  80      // ushorts per h row (160 B)
#define BUFB  (MB*HSTR)   // 640 ushorts per buffer

#define NLOG2E  1.4426950408889634f   // gates scaled by -log2e (g-gate by -2log2e) in B
#define N2LOG2E 2.8853900817779268f

typedef __attribute__((ext_vector_type(8))) _Float16 half8;
typedef __attribute__((ext_vector_type(4))) float    f32x4;

__device__ __forceinline__ ushort f16b(float f){ return __half_as_ushort(__float2half(f)); }
__device__ __forceinline__ float rcp_(float x){ return __builtin_amdgcn_rcpf(x); }
__device__ __forceinline__ float ex2_(float x){ return __builtin_amdgcn_exp2f(x); }
// lane l <-> lane l^8 swap at VALU speed (DPP row_ror:8), no LDS pipe
__device__ __forceinline__ float dpp_swap8(float v){
    return __int_as_float(__builtin_amdgcn_mov_dpp(__float_as_int(v), 0x128, 0xF, 0xF, true));
}

// Bm[256 cols][64 k] f16.  col = w*32 + j*16 + c16 encodes unit u = 8w + (c16&7),
// gate g = 2j + (c16>>3)  (g: 0=i,1=f,2=g,3=o).  Row r = g*50+u.  Entries pre-scaled
// by -log2e (g-gate by -2log2e) so MFMA emits gates in exp2 domain:
//   k<50: s*W_hh[r][k];  k in 50..62: s*embed[k-50]·W_ih[r];  k==63: s*(b_ih+b_hh)[r].
__global__ void build_B(const float* __restrict__ embed, const float* __restrict__ Wih,
                        const float* __restrict__ Whh, const float* __restrict__ bih,
                        const float* __restrict__ bhh, ushort* __restrict__ Bm) {
    int idx = blockIdx.x * blockDim.x + threadIdx.x;
    if (idx >= 256 * KP) return;
    int col = idx >> 6, k = idx & 63;
    int w = col >> 5, j = (col >> 4) & 1, cc = col & 15;
    int g = 2 * j + (cc >> 3);
    int u = 8 * w + (cc & 7);
    ushort v = 0;
    if (u < HID) {
        int r = g * HID + u;
        float s = (g == 2) ? -N2LOG2E : -NLOG2E;
        if (k < HID) {
            v = f16b(s * Whh[r * HID + k]);
        } else if (k < 63) {
            float t = 0.f;
            for (int e = 0; e < HID; ++e)
                t = fmaf(embed[(k - 50) * HID + e], Wih[r * HID + e], t);
            v = f16b(s * t);
        } else {
            v = f16b(s * (bih[r] + bhh[r]));
        }
    }
    Bm[idx] = v;
}

// 8 waves (2/SIMD), MB=8, 1 block/CU. Per wave: 2 N-tiles = 4 independent MFMAs.
// A rows = h[m>>1] (2x dup): lane (q,c16) holds rows 2q (z[0]) and 2q+1 (z[2]) of
// gates {i|f, g|o}; one dpp row_ror:8 swap completes the 4-gate set for ONE row per
// lane -> 1 activation/lane. Tokens cached in LDS: zero global ops in the loop.
__global__ __launch_bounds__(NTHR, 2) void lstm8w(
    const int*    __restrict__ x,
    const ushort* __restrict__ Bm,
    const float*  __restrict__ W1,
    const float*  __restrict__ b1,
    const float*  __restrict__ W2,
    const float*  __restrict__ b2,
    float*        __restrict__ out)
{
    const int t    = threadIdx.x;
    const int w    = t >> 6;          // wave 0..7
    const int l    = t & 63;
    const int q    = l >> 4;
    const int c16  = l & 15;
    const bool lo  = (c16 < 8);
    const int u    = 8 * w + (c16 & 7);        // unit handled by this lane
    const int myrow = 2 * q + (lo ? 0 : 1);    // batch row handled by this lane

    __shared__ __align__(16) ushort hbuf[2 * BUFB];            // 2560 B
    __shared__ __align__(16) unsigned char tokL[MB * T_SEQ];   // 16 KiB
    __shared__ float zb[HID * MB];                             // 1600 B

    // B fragments: wave w owns tiles 2w (gates i/f), 2w+1 (gates g/o), col c16
    half8 bf[2][2];
    {
        const ushort* bp = Bm + (w * 32 + c16) * KP + q * 8;
        #pragma unroll
        for (int j = 0; j < 2; ++j) {
            bf[j][0] = *(const half8*)(bp + j * 16 * KP);
            bf[j][1] = *(const half8*)(bp + j * 16 * KP + 32);
        }
    }
    asm volatile("" : "+v"(bf[0][0]), "+v"(bf[0][1]), "+v"(bf[1][0]), "+v"(bf[1][1]));

    // Token preload: 8 consecutive rows -> coalesced int4, pack to u8
    {
        const int4* xs = (const int4*)(x + (long)blockIdx.x * MB * T_SEQ);
        for (int i = t; i < MB * T_SEQ / 4; i += NTHR) {
            int4 v = xs[i];
            uint pk = (uint)(v.x & 0xFF) | ((uint)(v.y & 0xFF) << 8) |
                      ((uint)(v.z & 0xFF) << 16) | ((uint)(v.w & 0xFF) << 24);
            *(uint*)(tokL + i * 4) = pk;
        }
    }
    for (int i = t; i < 2 * BUFB; i += NTHR) hbuf[i] = 0;
    __syncthreads();

    // init bias + step-0/1 onehots; wave w maintains batch row w
    int tk0 = tokL[w * T_SEQ + 0];
    int tk1 = tokL[w * T_SEQ + 1];
    if (l == 0) {
        hbuf[0 * BUFB + w * HSTR + 63] = 0x3C00;
        hbuf[1 * BUFB + w * HSTR + 63] = 0x3C00;
        hbuf[0 * BUFB + w * HSTR + 50 + tk0] = 0x3C00;
        hbuf[1 * BUFB + w * HSTR + 50 + tk1] = 0x3C00;
    }
    int t0r = tk1, t1r = tk0, t2r = tk1;   // clear(t-1)/set(t+1) rolling window
    __syncthreads();

    // A row m = h[m>>1]: lane pairs broadcast
    const ushort* ar  = hbuf + (c16 >> 1) * HSTR + q * 8;
    ushort*       wr_ = hbuf + myrow * HSTR + u;       // h write: row myrow, unit u
    const unsigned char* tp = tokL + w * T_SEQ;

    float cs = 0.f;                        // cs = -2*log2e * c  (pre-scaled domain)

#define MFMA_(A,B,C) __builtin_amdgcn_mfma_f32_16x16x32_f16((A),(B),(C),0,0,0)
#define STEP(P) do {                                                              \
        int it = step + 2 + (P); if (it > T_SEQ - 1) it = T_SEQ - 1;              \
        int tn = tp[it];                       /* LDS broadcast read */           \
        half8 a0 = *(const half8*)(ar + (P) * BUFB);                              \
        half8 a1 = *(const half8*)(ar + (P) * BUFB + 32);                         \
        const f32x4 zz = {0.f, 0.f, 0.f, 0.f};                                    \
        __builtin_amdgcn_s_setprio(1);                                            \
        f32x4 z0a = MFMA_(a0, bf[0][0], zz);   /* independent pair: no C chain */ \
        f32x4 z0b = MFMA_(a1, bf[0][1], zz);                                      \
        f32x4 z1a = MFMA_(a0, bf[1][0], zz);                                      \
        f32x4 z1b = MFMA_(a1, bf[1][1], zz);                                      \
        __builtin_amdgcn_s_setprio(0);                                            \
        float s0l = z0a[0] + z0b[0];           /* gate(i|f), row 2q   */          \
        float s0h = z0a[2] + z0b[2];           /* gate(i|f), row 2q+1 */          \
        float s1l = z1a[0] + z1b[0];           /* gate(g|o), row 2q   */          \
        float s1h = z1a[2] + z1b[2];           /* gate(g|o), row 2q+1 */          \
        float rx0 = dpp_swap8(lo ? s0h : s0l); /* partner's complement gates */   \
        float rx1 = dpp_swap8(lo ? s1h : s1l);                                    \
        float gi = lo ? s0l : rx0;             /* all 4 gates of row myrow */     \
        float gf = lo ? rx0 : s0h;                                                \
        float gg = lo ? s1l : rx1;                                                \
        float go = lo ? rx1 : s1h;                                                \
        /* gates arrive exp2-scaled; clamp caps inf*0 NaN paths */                \
        float pi = ex2_(fminf(gi, 30.f));                                         \
        float pf = ex2_(fminf(gf, 30.f));                                         \
        float qg = ex2_(fminf(gg, 30.f));                                         \
        float Df = 1.f + pf;                                                      \
        float D2 = (1.f + pi) * (1.f + qg);                                       \
        float ivA = rcp_(Df * D2);                                                \
        float fv  = ivA * D2;                  /* sigm(gf) */                     \
        float igs = ivA * Df * fmaf(N2LOG2E, qg, -N2LOG2E); /* -2log2e*i*g */     \
        cs = fmaf(fv, cs, igs);                                                   \
        float po = ex2_(fminf(go, 30.f));                                         \
        float qc = ex2_(fminf(cs, 30.f));      /* e^-2c = 2^cs */                 \
        float ivB = rcp_((1.f + po) * (1.f + qc));                                \
        float hh  = ivB * (1.f - qc);          /* sigm(go)*tanh(c) */             \
        if (u < HID) wr_[(1 - (P)) * BUFB] = f16b(hh);                            \
        if (l == 0) {                                                             \
            ushort* hb = hbuf + (1 - (P)) * BUFB + w * HSTR + 50;                 \
            hb[t0r] = 0;                                                          \
            hb[t2r] = 0x3C00;                                                     \
        }                                                                         \
        t0r = t1r; t1r = t2r; t2r = tn;                                           \
        __syncthreads();                                                          \
    } while (0)

    #pragma unroll 1
    for (int step = 0; step < T_SEQ; step += 2) {
        STEP(0);
        STEP(1);
    }
#undef STEP
#undef MFMA_

    // Epilogue MLP: final h in buffer 0 (last step wrote it), already synced.
    if (t < MB * HID) {   // 400 threads
        int m = t & 7, uu = t >> 3;
        float a = b1[uu];
        const ushort* hr = hbuf + m * HSTR;
        #pragma unroll 10
        for (int k = 0; k < HID; ++k)
            a = fmaf(W1[uu * HID + k], __half2float(__ushort_as_half(hr[k])), a);
        zb[uu * MB + m] = fmaxf(a, 0.f);
    }
    __syncthreads();
    if (t < MB) {
        float a = b2[0];
        #pragma unroll 10
        for (int j = 0; j < HID; ++j)
            a = fmaf(W2[j], zb[j * MB + t], a);
        out[blockIdx.x * MB + t] = a;
    }
}

extern "C" void kernel_launch(void* const* d_in, const int* in_sizes, int n_in,
                              void* d_out, int out_size, void* d_ws, size_t ws_size,
                              hipStream_t stream) {
    const int*   x     = (const int*)  d_in[0];
    const float* embed = (const float*)d_in[1];
    const float* W_ih  = (const float*)d_in[2];
    const float* W_hh  = (const float*)d_in[3];
    const float* b_ih  = (const float*)d_in[4];
    const float* b_hh  = (const float*)d_in[5];
    const float* W1    = (const float*)d_in[6];
    const float* b1    = (const float*)d_in[7];
    const float* W2    = (const float*)d_in[8];
    const float* b2    = (const float*)d_in[9];
    float* out = (float*)d_out;

    ushort* Bm = (ushort*)d_ws;   // 256*64*2 = 32768 B scratch

    build_B<<<(256 * KP + 255) / 256, 256, 0, stream>>>(
        embed, W_ih, W_hh, b_ih, b_hh, Bm);

    lstm8w<<<NBLK, NTHR, 0, stream>>>(
        x, Bm, W1, b1, W2, b2, out);
}

// Round 8
// 703.928 us; speedup vs baseline: 1.3553x; 1.0631x over previous
//
#include <hip/hip_runtime.h>
#include <hip/hip_fp16.h>

#define T_SEQ 2048
#define HID   50
#define KP    64      // k: 0..49 = h, 50..62 = onehot, 63 = bias
#define MB    8       // batch rows per block (16 A-rows = 8 real x 2 dup)
#define NBLK  256     // 2048 / MB -> 1 block/CU
#define NTHR  512     // 8 waves -> 2 waves/SIMD
#define HSTR  80      // ushorts per h row (160 B)
#define BUFB  (MB*HSTR)   // 640 ushorts per buffer

#define NLOG2E  1.4426950408889634f   // gates scaled by -log2e (g-gate by -2log2e) in B
#define N2LOG2E 2.8853900817779268f

typedef __attribute__((ext_vector_type(8))) _Float16 half8;
typedef __attribute__((ext_vector_type(4))) float    f32x4;

__device__ __forceinline__ ushort f16b(float f){ return __half_as_ushort(__float2half(f)); }
__device__ __forceinline__ float rcp_(float x){ return __builtin_amdgcn_rcpf(x); }
__device__ __forceinline__ float ex2_(float x){ return __builtin_amdgcn_exp2f(x); }
// lane l <-> lane l^8 swap at VALU speed (DPP row_ror:8), no LDS pipe
__device__ __forceinline__ float dpp_swap8(float v){
    return __int_as_float(__builtin_amdgcn_mov_dpp(__float_as_int(v), 0x128, 0xF, 0xF, true));
}

// Bm[256 cols][64 k] f16.  col = w*32 + j*16 + c16 encodes unit u = 8w + (c16&7),
// gate g = 2j + (c16>>3)  (g: 0=i,1=f,2=g,3=o).  Row r = g*50+u.  Entries pre-scaled
// by -log2e (g-gate by -2log2e) so MFMA emits gates in exp2 domain:
//   k<50: s*W_hh[r][k];  k in 50..62: s*embed[k-50]·W_ih[r];  k==63: s*(b_ih+b_hh)[r].
__global__ void build_B(const float* __restrict__ embed, const float* __restrict__ Wih,
                        const float* __restrict__ Whh, const float* __restrict__ bih,
                        const float* __restrict__ bhh, ushort* __restrict__ Bm) {
    int idx = blockIdx.x * blockDim.x + threadIdx.x;
    if (idx >= 256 * KP) return;
    int col = idx >> 6, k = idx & 63;
    int w = col >> 5, j = (col >> 4) & 1, cc = col & 15;
    int g = 2 * j + (cc >> 3);
    int u = 8 * w + (cc & 7);
    ushort v = 0;
    if (u < HID) {
        int r = g * HID + u;
        float s = (g == 2) ? -N2LOG2E : -NLOG2E;
        if (k < HID) {
            v = f16b(s * Whh[r * HID + k]);
        } else if (k < 63) {
            float t = 0.f;
            for (int e = 0; e < HID; ++e)
                t = fmaf(embed[(k - 50) * HID + e], Wih[r * HID + e], t);
            v = f16b(s * t);
        } else {
            v = f16b(s * (bih[r] + bhh[r]));
        }
    }
    Bm[idx] = v;
}

// 8 waves (2/SIMD), MB=8, 1 block/CU — the MFMA-minimal structure (32 MFMA/CU-step).
// This round: uniform issue trims — chained MFMA pairs (no z-adds), gate clamps dropped
// (bounded: |gate|<=~40 => products <= 2^120 < f32 max, no inf/NaN path), tokens on the
// scalar pipe (uniform s_load prefetch, SGPR window) instead of an LDS cache.
__global__ __launch_bounds__(NTHR, 2) void lstm8w(
    const int*    __restrict__ x,
    const ushort* __restrict__ Bm,
    const float*  __restrict__ W1,
    const float*  __restrict__ b1,
    const float*  __restrict__ W2,
    const float*  __restrict__ b2,
    float*        __restrict__ out)
{
    const int t    = threadIdx.x;
    const int w    = t >> 6;          // wave 0..7
    const int l    = t & 63;
    const int q    = l >> 4;
    const int c16  = l & 15;
    const bool lo  = (c16 < 8);
    const int u    = 8 * w + (c16 & 7);        // unit handled by this lane
    const int myrow = 2 * q + (lo ? 0 : 1);    // batch row handled by this lane
    const int wu   = __builtin_amdgcn_readfirstlane(w);  // uniform wave id -> s_load path

    __shared__ __align__(16) ushort hbuf[2 * BUFB];   // 2560 B
    __shared__ float zb[HID * MB];                    // 1600 B

    // B fragments: wave w owns tiles 2w (gates i/f), 2w+1 (gates g/o), col c16
    half8 bf[2][2];
    {
        const ushort* bp = Bm + (w * 32 + c16) * KP + q * 8;
        #pragma unroll
        for (int j = 0; j < 2; ++j) {
            bf[j][0] = *(const half8*)(bp + j * 16 * KP);
            bf[j][1] = *(const half8*)(bp + j * 16 * KP + 32);
        }
    }
    asm volatile("" : "+v"(bf[0][0]), "+v"(bf[0][1]), "+v"(bf[1][0]), "+v"(bf[1][1]));

    for (int i = t; i < 2 * BUFB; i += NTHR) hbuf[i] = 0;

    // wave-uniform token stream for batch row (blockIdx*8 + wu)
    const int* xw = x + ((long)blockIdx.x * MB + wu) * T_SEQ;
    int tk0 = xw[0];
    int tk1 = xw[1];
    __syncthreads();
    if (l == 0) {
        hbuf[0 * BUFB + wu * HSTR + 63] = 0x3C00;        // bias slot = 1.0
        hbuf[1 * BUFB + wu * HSTR + 63] = 0x3C00;
        hbuf[0 * BUFB + wu * HSTR + 50 + tk0] = 0x3C00;  // onehot step 0
        hbuf[1 * BUFB + wu * HSTR + 50 + tk1] = 0x3C00;  // onehot step 1
    }
    int t0r = tk1, t1r = tk0, t2r = tk1;   // clear(t-1)/set(t+1) rolling window (SGPR)
    __syncthreads();

    // A row m = h[m>>1]: lane pairs broadcast
    const ushort* ar  = hbuf + (c16 >> 1) * HSTR + q * 8;
    ushort*       wr_ = hbuf + myrow * HSTR + u;       // h write: row myrow, unit u
    ushort*       hbw = hbuf + wu * HSTR + 50;         // token window base (uniform)

    float cs = 0.f;                        // cs = -2*log2e * c  (pre-scaled domain)

#define MFMA_(A,B,C) __builtin_amdgcn_mfma_f32_16x16x32_f16((A),(B),(C),0,0,0)
#define STEP(P) do {                                                              \
        int it = step + 2 + (P); if (it > T_SEQ - 1) it = T_SEQ - 1;              \
        int tn = xw[it];                       /* uniform s_load prefetch */      \
        half8 a0 = *(const half8*)(ar + (P) * BUFB);                              \
        half8 a1 = *(const half8*)(ar + (P) * BUFB + 32);                         \
        const f32x4 zz = {0.f, 0.f, 0.f, 0.f};                                    \
        __builtin_amdgcn_s_setprio(1);                                            \
        f32x4 z0 = MFMA_(a0, bf[0][0], zz);                                       \
        z0 = MFMA_(a1, bf[0][1], z0);          /* chained: add in MFMA pipe */    \
        f32x4 z1 = MFMA_(a0, bf[1][0], zz);                                       \
        z1 = MFMA_(a1, bf[1][1], z1);                                             \
        __builtin_amdgcn_s_setprio(0);                                            \
        float s0l = z0[0];                     /* gate(i|f), row 2q   */          \
        float s0h = z0[2];                     /* gate(i|f), row 2q+1 */          \
        float s1l = z1[0];                     /* gate(g|o), row 2q   */          \
        float s1h = z1[2];                     /* gate(g|o), row 2q+1 */          \
        float rx0 = dpp_swap8(lo ? s0h : s0l); /* partner's complement gates */   \
        float rx1 = dpp_swap8(lo ? s1h : s1l);                                    \
        float gi = lo ? s0l : rx0;             /* all 4 gates of row myrow */     \
        float gf = lo ? rx0 : s0h;                                                \
        float gg = lo ? s1l : rx1;                                                \
        float go = lo ? rx1 : s1h;                                                \
        /* gates arrive exp2-scaled; bounded (<=~40) so no clamps needed */       \
        float pi = ex2_(gi);                                                      \
        float pf = ex2_(gf);                                                      \
        float qg = ex2_(gg);                                                      \
        float Df = 1.f + pf;                                                      \
        float D2 = (1.f + pi) * (1.f + qg);                                       \
        float ivA = rcp_(Df * D2);                                                \
        float fv  = ivA * D2;                  /* sigm(gf) */                     \
        float igs = ivA * Df * fmaf(N2LOG2E, qg, -N2LOG2E); /* -2log2e*i*g */     \
        cs = fmaf(fv, cs, igs);                                                   \
        float po = ex2_(go);                                                      \
        float qc = ex2_(fminf(cs, 30.f));      /* e^-2c = 2^cs; cs accumulates */ \
        float ivB = rcp_((1.f + po) * (1.f + qc));                                \
        float hh  = ivB * (1.f - qc);          /* sigm(go)*tanh(c) */             \
        if (u < HID) wr_[(1 - (P)) * BUFB] = f16b(hh);                            \
        if (l == 0) {                                                             \
            ushort* hb = hbw + (1 - (P)) * BUFB;                                  \
            hb[t0r] = 0;                                                          \
            hb[t2r] = 0x3C00;                                                     \
        }                                                                         \
        t0r = t1r; t1r = t2r; t2r = tn;        /* SGPR shifts */                  \
        __syncthreads();                                                          \
    } while (0)

    #pragma unroll 1
    for (int step = 0; step < T_SEQ; step += 2) {
        STEP(0);
        STEP(1);
    }
#undef STEP
#undef MFMA_

    // Epilogue MLP: final h in buffer 0 (last step wrote it), already synced.
    if (t < MB * HID) {   // 400 threads
        int m = t & 7, uu = t >> 3;
        float a = b1[uu];
        const ushort* hr = hbuf + m * HSTR;
        #pragma unroll 10
        for (int k = 0; k < HID; ++k)
            a = fmaf(W1[uu * HID + k], __half2float(__ushort_as_half(hr[k])), a);
        zb[uu * MB + m] = fmaxf(a, 0.f);
    }
    __syncthreads();
    if (t < MB) {
        float a = b2[0];
        #pragma unroll 10
        for (int j = 0; j < HID; ++j)
            a = fmaf(W2[j], zb[j * MB + t], a);
        out[blockIdx.x * MB + t] = a;
    }
}

extern "C" void kernel_launch(void* const* d_in, const int* in_sizes, int n_in,
                              void* d_out, int out_size, void* d_ws, size_t ws_size,
                              hipStream_t stream) {
    const int*   x     = (const int*)  d_in[0];
    const float* embed = (const float*)d_in[1];
    const float* W_ih  = (const float*)d_in[2];
    const float* W_hh  = (const float*)d_in[3];
    const float* b_ih  = (const float*)d_in[4];
    const float* b_hh  = (const float*)d_in[5];
    const float* W1    = (const float*)d_in[6];
    const float* b1    = (const float*)d_in[7];
    const float* W2    = (const float*)d_in[8];
    const float* b2    = (const float*)d_in[9];
    float* out = (float*)d_out;

    ushort* Bm = (ushort*)d_ws;   // 256*64*2 = 32768 B scratch

    build_B<<<(256 * KP + 255) / 256, 256, 0, stream>>>(
        embed, W_ih, W_hh, b_ih, b_hh, Bm);

    lstm8w<<<NBLK, NTHR, 0, stream>>>(
        x, Bm, W1, b1, W2, b2, out);
}